// Round 7
// baseline (396.448 us; speedup 1.0000x reference)
//
#include <hip/hip_runtime.h>
#include <hip/hip_fp16.h>

#define C  64
#define C8 8
#define EPSV 1e-5f
// k = int(0.6*64) = 38 -> threshold = 38th largest = ascending index 26

__device__ __forceinline__ float silu_f(float v) {
    return v * (1.f / (1.f + __expf(-v)));
}

// Round-7 = round-0 structure (1 location/thread, t[64] in-register bitonic,
// ZERO cross-lane ops in phase 2 - the fastest structure measured, 117 us)
// with its VGPR defect fixed by validated pieces only:
//   - a[64] dropped: epilogue recomputes attn with identical FMA order
//     (bitwise-equal values -> exact mask; validated r1/r2).
//   - xs dropped from LDS: phase 2 reads x from global. With the XCD swizzle
//     (validated r6: FETCH 161->35 MB) those reads are L2/L3-hot.
//   - NO __launch_bounds__: the (256,N) hint caps VGPR at 256/N and
//     cliff-spills (r1: 64 regs/+745 MB scratch; r2: 84/+490 MB).
//     Natural allocation for the slimmed live set (~110) should land
//     120-160 -> 3-4 waves/SIMD vs r0's 2.
// LDS: y1s [c][256 fp16], chunk-XOR swizzle (elem (c,loc) at
//   c*256 + (loc ^ ((c&7)*8)), conflict-free both phases, validated r0)
//   = 32 KB, + wt 6.4 KB = 38.4 KB -> up to 4 blocks/CU.
__global__ void fused_kernel(
    const float* __restrict__ x, const float* __restrict__ w_dw,
    const float* __restrict__ g1, const float* __restrict__ be1,
    const float* __restrict__ mu1, const float* __restrict__ va1,
    const float* __restrict__ w1, const float* __restrict__ b1,
    const float* __restrict__ g2, const float* __restrict__ be2,
    const float* __restrict__ mu2, const float* __restrict__ va2,
    const float* __restrict__ w2, const float* __restrict__ b2,
    const float* __restrict__ alphap, float* __restrict__ out)
{
    __shared__ __align__(16) __half y1s[C * 256];   // 32 KB
    __shared__ float wt[C * 25];                    // 6.4 KB, conv weights

    // XCD-aware swizzle (1024 % 8 == 0 -> bijective): XCD k gets logical
    // blocks [k*128,(k+1)*128) -> adjacent h-bands (shared halo rows, shared
    // phase-2 x lines) run on the same XCD's L2.  Validated r6.
    const int hw  = blockIdx.x;
    const int blk = (hw & 7) * 128 + (hw >> 3);   // 1024 = b*256 + d*16 + hb
    const int hb  = blk & 15;
    const int d   = (blk >> 4) & 15;
    const int b   = blk >> 8;
    const int h0  = hb * 4;
    const int tid = threadIdx.x;

    for (int i = tid; i < C * 25; i += 256) wt[i] = w_dw[i];
    __syncthreads();

    // ---------------- phase 1: depthwise conv rows h0..h0+3 -> y1 to LDS
    {
        const int c     = tid >> 2;        // 0..63
        const int strip = tid & 3;
        const int w16   = strip * 16;      // output cols w16..w16+15
        const int q     = w16 >> 2;

        const float scale = g1[c] * rsqrtf(va1[c] + EPSV);
        const float shift = be1[c] - mu1[c] * scale;
        const long xbase = ((long)(b * C + c) * 16 + d) * 4096;

        float acc[4][16];
#pragma unroll
        for (int i = 0; i < 4; ++i)
#pragma unroll
            for (int ow = 0; ow < 16; ++ow) acc[i][ow] = 0.f;

#pragma unroll
        for (int j = 0; j < 8; ++j) {      // input row r = h0 + j - 2
            const int r = h0 + j - 2;
            if (r >= 0 && r < 64) {
                const float4* rowp = (const float4*)(x + xbase + r * 64);
                const float4 z = make_float4(0.f, 0.f, 0.f, 0.f);
                float4 u0 = (q > 0)  ? rowp[q - 1] : z;
                float4 u1 = rowp[q];
                float4 u2 = rowp[q + 1];
                float4 u3 = rowp[q + 2];
                float4 u4 = rowp[q + 3];
                float4 u5 = (q < 12) ? rowp[q + 4] : z;
                // vals[v] = x[row r, col w16 - 4 + v]
                float vals[24] = {u0.x,u0.y,u0.z,u0.w, u1.x,u1.y,u1.z,u1.w,
                                  u2.x,u2.y,u2.z,u2.w, u3.x,u3.y,u3.z,u3.w,
                                  u4.x,u4.y,u4.z,u4.w, u5.x,u5.y,u5.z,u5.w};
#pragma unroll
                for (int i = 0; i < 4; ++i) {
                    if (i <= j && (j - i) <= 4) {   // kernel row kr = j - i
                        const int kr = j - i;
                        const float* wrow = &wt[c * 25 + kr * 5];
#pragma unroll
                        for (int kc = 0; kc < 5; ++kc) {
                            const float kw = wrow[kc];
#pragma unroll
                            for (int ow = 0; ow < 16; ++ow)
                                acc[i][ow] += kw * vals[ow + kc + 2];
                        }
                    }
                }
            }
        }
        const int csw = (c & 7);           // chunk-XOR term
#pragma unroll
        for (int i = 0; i < 4; ++i) {
            float o[16];
#pragma unroll
            for (int ow = 0; ow < 16; ++ow)
                o[ow] = silu_f(acc[i][ow] * scale + shift);
            const int chunkbase = i * 8 + 2 * strip;
#pragma unroll
            for (int t = 0; t < 2; ++t) {
                const int p = (chunkbase + t) ^ csw;
                union { __half2 h[4]; float4 f; } u;
#pragma unroll
                for (int m = 0; m < 4; ++m)
                    u.h[m] = __floats2half2_rn(o[t * 8 + 2 * m], o[t * 8 + 2 * m + 1]);
                *(float4*)&y1s[c * 256 + p * 8] = u.f;
            }
        }
    }
    __syncthreads();

    // ---------------- phase 2: pw1 + BN2 + SiLU + pw2, attn, top-k, epilogue
    {
        const int loc = tid;
        const int rg  = d * 4096 + (h0 + (tid >> 6)) * 64 + (tid & 63);
        const long xoff = (long)b * (C * 65536) + rg;   // x/out share layout

        // pw1 from global x (coalesced; L2/L3-hot under XCD swizzle).
        // Double-buffered groups of 8 -> 8 loads in flight, bounded regs.
        float s1[C8];
#pragma unroll
        for (int o = 0; o < C8; ++o) s1[o] = 0.f;
        float xg[2][8];
#pragma unroll
        for (int u = 0; u < 8; ++u) xg[0][u] = x[xoff + (long)u * 65536];
#pragma unroll
        for (int g = 0; g < 8; ++g) {
            const int cur = g & 1;
            if (g < 7) {
#pragma unroll
                for (int u = 0; u < 8; ++u)
                    xg[cur ^ 1][u] = x[xoff + (long)((g + 1) * 8 + u) * 65536];
            }
#pragma unroll
            for (int u = 0; u < 8; ++u) {
                const int ch = g * 8 + u;
                const float xc = xg[cur][u];
#pragma unroll
                for (int o = 0; o < C8; ++o) s1[o] += w1[o * C + ch] * xc;
            }
        }
        float hh[C8];
#pragma unroll
        for (int o = 0; o < C8; ++o) {
            const float sc = g2[o] * rsqrtf(va2[o] + EPSV);
            hh[o] = silu_f((s1[o] + b1[o] - mu2[o]) * sc + be2[o]);
        }

        // attn values (sort scratch only; epilogue recomputes identically)
        float t[C];
#pragma unroll
        for (int c = 0; c < C; ++c) {
            const float y1v = __half2float(y1s[c * 256 + (loc ^ ((c & 7) << 3))]);
            float y2 = b2[c];
#pragma unroll
            for (int o = 0; o < C8; ++o) y2 += w2[c * C8 + o] * hh[o];
            t[c] = y1v * y2;
        }

        // in-register bitonic sort (ascending) of 64 values — shuffle-free
#pragma unroll
        for (int k = 2; k <= 64; k <<= 1) {
#pragma unroll
            for (int j = k >> 1; j > 0; j >>= 1) {
#pragma unroll
                for (int i = 0; i < 64; ++i) {
                    const int l = i ^ j;
                    if (l > i) {
                        const float u = t[i], v = t[l];
                        const float mn = fminf(u, v), mx = fmaxf(u, v);
                        if ((i & k) == 0) { t[i] = mn; t[l] = mx; }
                        else              { t[i] = mx; t[l] = mn; }
                    }
                }
            }
        }
        const float thr = t[26];          // 38th largest of 64
        const float alpha = alphap[0];

        float* op = out + xoff;

        // epilogue: recompute attn (identical FMA order -> bitwise equal to
        // sorted values); x re-read from global (L1/L2-hot), groups of 8
#pragma unroll
        for (int u = 0; u < 8; ++u) xg[0][u] = x[xoff + (long)u * 65536];
#pragma unroll
        for (int g = 0; g < 8; ++g) {
            const int cur = g & 1;
            if (g < 7) {
#pragma unroll
                for (int u = 0; u < 8; ++u)
                    xg[cur ^ 1][u] = x[xoff + (long)((g + 1) * 8 + u) * 65536];
            }
#pragma unroll
            for (int u = 0; u < 8; ++u) {
                const int ch = g * 8 + u;
                const float y1v = __half2float(y1s[ch * 256 + (loc ^ ((ch & 7) << 3))]);
                float y2 = b2[ch];
#pragma unroll
                for (int o = 0; o < C8; ++o) y2 += w2[ch * C8 + o] * hh[o];
                const float av = y1v * y2;
                op[(long)ch * 65536] = xg[cur][u] + ((av >= thr) ? alpha * av : 0.f);
            }
        }
    }
}

extern "C" void kernel_launch(void* const* d_in, const int* in_sizes, int n_in,
                              void* d_out, int out_size, void* d_ws, size_t ws_size,
                              hipStream_t stream) {
    const float* x    = (const float*)d_in[0];
    const float* w_dw = (const float*)d_in[1];
    const float* g1   = (const float*)d_in[2];
    const float* be1  = (const float*)d_in[3];
    const float* mu1  = (const float*)d_in[4];
    const float* va1  = (const float*)d_in[5];
    const float* w1   = (const float*)d_in[6];
    const float* b1   = (const float*)d_in[7];
    const float* g2   = (const float*)d_in[8];
    const float* be2  = (const float*)d_in[9];
    const float* mu2  = (const float*)d_in[10];
    const float* va2  = (const float*)d_in[11];
    const float* w2   = (const float*)d_in[12];
    const float* b2   = (const float*)d_in[13];
    const float* alp  = (const float*)d_in[14];
    float* out = (float*)d_out;

    // grid: b(4) x d(16) x h-band(16) = 1024 blocks (XCD-swizzled in-kernel)
    fused_kernel<<<1024, 256, 0, stream>>>(
        x, w_dw, g1, be1, mu1, va1, w1, b1, g2, be2, mu2, va2, w2, b2, alp, out);
}

// Round 9
// 238.281 us; speedup vs baseline: 1.6638x; 1.6638x over previous
//
#include <hip/hip_runtime.h>
#include <hip/hip_fp16.h>

#define C  64
#define C8 8
#define EPSV 1e-5f
// k = int(0.6*64) = 38 -> threshold = 38th largest = ascending index 26

__device__ __forceinline__ float silu_f(float v) {
    return v * (1.f / (1.f + __expf(-v)));
}

// Round-9 = round-8 resubmission (container infra failure, kernel unjudged).
// Structure: r0's 1-location/thread, t[64] in-register bitonic, zero
// cross-lane ops; a[64] dropped via epilogue recompute; x from global in
// phase 2; XCD swizzle; __launch_bounds__(256,2).
//
// Measured VGPR ladder on this compiler: default/(256,4)->64, (256,3)->84
// (all cliff-spill), (256)->224 (no spill, 2 waves/SIMD), (256,2)->128.
// This structure's live set is ~105 (phase1: acc[4][16]+vals[24]+addr;
// phase2: t[64]+hh[8]+addr; xg[16] and sort don't overlap) -> fits 128
// with headroom (unlike r4's ~142-live t[32] structure which spilled).
// 128 VGPR -> 4 waves/SIMD (HW pool 512); LDS 38.4 KB -> 4 blocks/CU:
// 16 waves/CU with the shortest critical path of any round.
__global__ __launch_bounds__(256, 2) void fused_kernel(
    const float* __restrict__ x, const float* __restrict__ w_dw,
    const float* __restrict__ g1, const float* __restrict__ be1,
    const float* __restrict__ mu1, const float* __restrict__ va1,
    const float* __restrict__ w1, const float* __restrict__ b1,
    const float* __restrict__ g2, const float* __restrict__ be2,
    const float* __restrict__ mu2, const float* __restrict__ va2,
    const float* __restrict__ w2, const float* __restrict__ b2,
    const float* __restrict__ alphap, float* __restrict__ out)
{
    __shared__ __align__(16) __half y1s[C * 256];   // 32 KB
    __shared__ float wt[C * 25];                    // 6.4 KB, conv weights

    // XCD-aware swizzle (1024 % 8 == 0 -> bijective): XCD k gets logical
    // blocks [k*128,(k+1)*128) -> adjacent h-bands share halo rows and
    // phase-2 x lines within one XCD's L2.  Validated r6.
    const int hw  = blockIdx.x;
    const int blk = (hw & 7) * 128 + (hw >> 3);   // 1024 = b*256 + d*16 + hb
    const int hb  = blk & 15;
    const int d   = (blk >> 4) & 15;
    const int b   = blk >> 8;
    const int h0  = hb * 4;
    const int tid = threadIdx.x;

    for (int i = tid; i < C * 25; i += 256) wt[i] = w_dw[i];
    __syncthreads();

    // ---------------- phase 1: depthwise conv rows h0..h0+3 -> y1 to LDS
    {
        const int c     = tid >> 2;        // 0..63
        const int strip = tid & 3;
        const int w16   = strip * 16;      // output cols w16..w16+15
        const int q     = w16 >> 2;

        const float scale = g1[c] * rsqrtf(va1[c] + EPSV);
        const float shift = be1[c] - mu1[c] * scale;
        const long xbase = ((long)(b * C + c) * 16 + d) * 4096;

        float acc[4][16];
#pragma unroll
        for (int i = 0; i < 4; ++i)
#pragma unroll
            for (int ow = 0; ow < 16; ++ow) acc[i][ow] = 0.f;

#pragma unroll
        for (int j = 0; j < 8; ++j) {      // input row r = h0 + j - 2
            const int r = h0 + j - 2;
            if (r >= 0 && r < 64) {
                const float4* rowp = (const float4*)(x + xbase + r * 64);
                const float4 z = make_float4(0.f, 0.f, 0.f, 0.f);
                float4 u0 = (q > 0)  ? rowp[q - 1] : z;
                float4 u1 = rowp[q];
                float4 u2 = rowp[q + 1];
                float4 u3 = rowp[q + 2];
                float4 u4 = rowp[q + 3];
                float4 u5 = (q < 12) ? rowp[q + 4] : z;
                // vals[v] = x[row r, col w16 - 4 + v]
                float vals[24] = {u0.x,u0.y,u0.z,u0.w, u1.x,u1.y,u1.z,u1.w,
                                  u2.x,u2.y,u2.z,u2.w, u3.x,u3.y,u3.z,u3.w,
                                  u4.x,u4.y,u4.z,u4.w, u5.x,u5.y,u5.z,u5.w};
#pragma unroll
                for (int i = 0; i < 4; ++i) {
                    if (i <= j && (j - i) <= 4) {   // kernel row kr = j - i
                        const int kr = j - i;
                        const float* wrow = &wt[c * 25 + kr * 5];
#pragma unroll
                        for (int kc = 0; kc < 5; ++kc) {
                            const float kw = wrow[kc];
#pragma unroll
                            for (int ow = 0; ow < 16; ++ow)
                                acc[i][ow] += kw * vals[ow + kc + 2];
                        }
                    }
                }
            }
        }
        const int csw = (c & 7);           // chunk-XOR term
#pragma unroll
        for (int i = 0; i < 4; ++i) {
            float o[16];
#pragma unroll
            for (int ow = 0; ow < 16; ++ow)
                o[ow] = silu_f(acc[i][ow] * scale + shift);
            const int chunkbase = i * 8 + 2 * strip;
#pragma unroll
            for (int t = 0; t < 2; ++t) {
                const int p = (chunkbase + t) ^ csw;
                union { __half2 h[4]; float4 f; } u;
#pragma unroll
                for (int m = 0; m < 4; ++m)
                    u.h[m] = __floats2half2_rn(o[t * 8 + 2 * m], o[t * 8 + 2 * m + 1]);
                *(float4*)&y1s[c * 256 + p * 8] = u.f;
            }
        }
    }
    __syncthreads();

    // ---------------- phase 2: pw1 + BN2 + SiLU + pw2, attn, top-k, epilogue
    {
        const int loc = tid;
        const int rg  = d * 4096 + (h0 + (tid >> 6)) * 64 + (tid & 63);
        const long xoff = (long)b * (C * 65536) + rg;   // x/out share layout

        // pw1 from global x (coalesced; L2/L3-hot under XCD swizzle).
        // Double-buffered groups of 8 -> 8 loads in flight, bounded regs.
        float s1[C8];
#pragma unroll
        for (int o = 0; o < C8; ++o) s1[o] = 0.f;
        float xg[2][8];
#pragma unroll
        for (int u = 0; u < 8; ++u) xg[0][u] = x[xoff + (long)u * 65536];
#pragma unroll
        for (int g = 0; g < 8; ++g) {
            const int cur = g & 1;
            if (g < 7) {
#pragma unroll
                for (int u = 0; u < 8; ++u)
                    xg[cur ^ 1][u] = x[xoff + (long)((g + 1) * 8 + u) * 65536];
            }
#pragma unroll
            for (int u = 0; u < 8; ++u) {
                const int ch = g * 8 + u;
                const float xc = xg[cur][u];
#pragma unroll
                for (int o = 0; o < C8; ++o) s1[o] += w1[o * C + ch] * xc;
            }
        }
        float hh[C8];
#pragma unroll
        for (int o = 0; o < C8; ++o) {
            const float sc = g2[o] * rsqrtf(va2[o] + EPSV);
            hh[o] = silu_f((s1[o] + b1[o] - mu2[o]) * sc + be2[o]);
        }

        // attn values (sort scratch only; epilogue recomputes identically)
        float t[C];
#pragma unroll
        for (int c = 0; c < C; ++c) {
            const float y1v = __half2float(y1s[c * 256 + (loc ^ ((c & 7) << 3))]);
            float y2 = b2[c];
#pragma unroll
            for (int o = 0; o < C8; ++o) y2 += w2[c * C8 + o] * hh[o];
            t[c] = y1v * y2;
        }

        // in-register bitonic sort (ascending) of 64 values — shuffle-free
#pragma unroll
        for (int k = 2; k <= 64; k <<= 1) {
#pragma unroll
            for (int j = k >> 1; j > 0; j >>= 1) {
#pragma unroll
                for (int i = 0; i < 64; ++i) {
                    const int l = i ^ j;
                    if (l > i) {
                        const float u = t[i], v = t[l];
                        const float mn = fminf(u, v), mx = fmaxf(u, v);
                        if ((i & k) == 0) { t[i] = mn; t[l] = mx; }
                        else              { t[i] = mx; t[l] = mn; }
                    }
                }
            }
        }
        const float thr = t[26];          // 38th largest of 64
        const float alpha = alphap[0];

        float* op = out + xoff;

        // epilogue: recompute attn (identical FMA order -> bitwise equal to
        // sorted values); x re-read from global (L1/L2-hot), groups of 8
#pragma unroll
        for (int u = 0; u < 8; ++u) xg[0][u] = x[xoff + (long)u * 65536];
#pragma unroll
        for (int g = 0; g < 8; ++g) {
            const int cur = g & 1;
            if (g < 7) {
#pragma unroll
                for (int u = 0; u < 8; ++u)
                    xg[cur ^ 1][u] = x[xoff + (long)((g + 1) * 8 + u) * 65536];
            }
#pragma unroll
            for (int u = 0; u < 8; ++u) {
                const int ch = g * 8 + u;
                const float y1v = __half2float(y1s[ch * 256 + (loc ^ ((ch & 7) << 3))]);
                float y2 = b2[ch];
#pragma unroll
                for (int o = 0; o < C8; ++o) y2 += w2[ch * C8 + o] * hh[o];
                const float av = y1v * y2;
                op[(long)ch * 65536] = xg[cur][u] + ((av >= thr) ? alpha * av : 0.f);
            }
        }
    }
}

extern "C" void kernel_launch(void* const* d_in, const int* in_sizes, int n_in,
                              void* d_out, int out_size, void* d_ws, size_t ws_size,
                              hipStream_t stream) {
    const float* x    = (const float*)d_in[0];
    const float* w_dw = (const float*)d_in[1];
    const float* g1   = (const float*)d_in[2];
    const float* be1  = (const float*)d_in[3];
    const float* mu1  = (const float*)d_in[4];
    const float* va1  = (const float*)d_in[5];
    const float* w1   = (const float*)d_in[6];
    const float* b1   = (const float*)d_in[7];
    const float* g2   = (const float*)d_in[8];
    const float* be2  = (const float*)d_in[9];
    const float* mu2  = (const float*)d_in[10];
    const float* va2  = (const float*)d_in[11];
    const float* w2   = (const float*)d_in[12];
    const float* b2   = (const float*)d_in[13];
    const float* alp  = (const float*)d_in[14];
    float* out = (float*)d_out;

    // grid: b(4) x d(16) x h-band(16) = 1024 blocks (XCD-swizzled in-kernel)
    fused_kernel<<<1024, 256, 0, stream>>>(
        x, w_dw, g1, be1, mu1, va1, w1, b1, g2, be2, mu2, va2, w2, b2, alp, out);
}

// Round 10
// 210.656 us; speedup vs baseline: 1.8820x; 1.1311x over previous
//
#include <hip/hip_runtime.h>
#include <hip/hip_fp16.h>

#define C  64
#define C8 8
#define EPSV 1e-5f
// k = int(0.6*64) = 38 -> threshold = 38th largest = ascending index 26

__device__ __forceinline__ float silu_f(float v) {
    return v * (1.f / (1.f + __expf(-v)));
}

// Round-10 = round-9 + `#pragma unroll 1` on the phase-1 row loop.
//
// r9 measured: VGPR=128 (cap honored) but ~88 MB scratch (84 dw/thread).
// Diagnosis: the fully-unrolled 8-row loop lets the pre-RA scheduler hoist
// ~40 float4 loads -> live ranges ~210 regs -> RA spills acc at the cap.
// The ARRAYS fit 128; the SCHEDULE didn't.  unroll 1 bounds the window to
// one row: 6 float4 in flight (24) + acc[4][16] (64) + vals reuse + addr
// ~= 105 live.  Costs: conv weights re-read from LDS per row (runtime kr*5
// offset, wave-uniform branches, ~200 ds_read_b32/thread) and cross-row
// MLP - both covered by 4 waves/SIMD TLP, which is what the 128 cap buys
// (16 waves/CU vs r0's 8, with r0's shuffle-free critical path).
//
// All inner loops stay statically unrolled: acc[i][ow] / vals[v] indices
// compile-time (rule #20: runtime-indexed arrays -> scratch).
__global__ __launch_bounds__(256, 2) void fused_kernel(
    const float* __restrict__ x, const float* __restrict__ w_dw,
    const float* __restrict__ g1, const float* __restrict__ be1,
    const float* __restrict__ mu1, const float* __restrict__ va1,
    const float* __restrict__ w1, const float* __restrict__ b1,
    const float* __restrict__ g2, const float* __restrict__ be2,
    const float* __restrict__ mu2, const float* __restrict__ va2,
    const float* __restrict__ w2, const float* __restrict__ b2,
    const float* __restrict__ alphap, float* __restrict__ out)
{
    __shared__ __align__(16) __half y1s[C * 256];   // 32 KB
    __shared__ float wt[C * 25];                    // 6.4 KB, conv weights

    // XCD-aware swizzle (1024 % 8 == 0 -> bijective): XCD k gets logical
    // blocks [k*128,(k+1)*128) -> adjacent h-bands share halo rows and
    // phase-2 x lines within one XCD's L2.  Validated r6.
    const int hw  = blockIdx.x;
    const int blk = (hw & 7) * 128 + (hw >> 3);   // 1024 = b*256 + d*16 + hb
    const int hb  = blk & 15;
    const int d   = (blk >> 4) & 15;
    const int b   = blk >> 8;
    const int h0  = hb * 4;
    const int tid = threadIdx.x;

    for (int i = tid; i < C * 25; i += 256) wt[i] = w_dw[i];
    __syncthreads();

    // ---------------- phase 1: depthwise conv rows h0..h0+3 -> y1 to LDS
    {
        const int c     = tid >> 2;        // 0..63
        const int strip = tid & 3;
        const int w16   = strip * 16;      // output cols w16..w16+15
        const int q     = w16 >> 2;

        const float scale = g1[c] * rsqrtf(va1[c] + EPSV);
        const float shift = be1[c] - mu1[c] * scale;
        const long xbase = ((long)(b * C + c) * 16 + d) * 4096;

        float acc[4][16];
#pragma unroll
        for (int i = 0; i < 4; ++i)
#pragma unroll
            for (int ow = 0; ow < 16; ++ow) acc[i][ow] = 0.f;

#pragma unroll 1
        for (int j = 0; j < 8; ++j) {      // input row r = h0 + j - 2
            const int r = h0 + j - 2;
            if (r >= 0 && r < 64) {
                const float4* rowp = (const float4*)(x + xbase + r * 64);
                const float4 z = make_float4(0.f, 0.f, 0.f, 0.f);
                float4 u0 = (q > 0)  ? rowp[q - 1] : z;
                float4 u1 = rowp[q];
                float4 u2 = rowp[q + 1];
                float4 u3 = rowp[q + 2];
                float4 u4 = rowp[q + 3];
                float4 u5 = (q < 12) ? rowp[q + 4] : z;
                // vals[v] = x[row r, col w16 - 4 + v]
                float vals[24] = {u0.x,u0.y,u0.z,u0.w, u1.x,u1.y,u1.z,u1.w,
                                  u2.x,u2.y,u2.z,u2.w, u3.x,u3.y,u3.z,u3.w,
                                  u4.x,u4.y,u4.z,u4.w, u5.x,u5.y,u5.z,u5.w};
#pragma unroll
                for (int i = 0; i < 4; ++i) {
                    if (i <= j && (j - i) <= 4) {   // kernel row kr = j - i
                        const int kr = j - i;      // wave-uniform branch
                        const float* wrow = &wt[c * 25 + kr * 5];
#pragma unroll
                        for (int kc = 0; kc < 5; ++kc) {
                            const float kw = wrow[kc];
#pragma unroll
                            for (int ow = 0; ow < 16; ++ow)
                                acc[i][ow] += kw * vals[ow + kc + 2];
                        }
                    }
                }
            }
        }
        const int csw = (c & 7);           // chunk-XOR term
#pragma unroll
        for (int i = 0; i < 4; ++i) {
            float o[16];
#pragma unroll
            for (int ow = 0; ow < 16; ++ow)
                o[ow] = silu_f(acc[i][ow] * scale + shift);
            const int chunkbase = i * 8 + 2 * strip;
#pragma unroll
            for (int t = 0; t < 2; ++t) {
                const int p = (chunkbase + t) ^ csw;
                union { __half2 h[4]; float4 f; } u;
#pragma unroll
                for (int m = 0; m < 4; ++m)
                    u.h[m] = __floats2half2_rn(o[t * 8 + 2 * m], o[t * 8 + 2 * m + 1]);
                *(float4*)&y1s[c * 256 + p * 8] = u.f;
            }
        }
    }
    __syncthreads();

    // ---------------- phase 2: pw1 + BN2 + SiLU + pw2, attn, top-k, epilogue
    {
        const int loc = tid;
        const int rg  = d * 4096 + (h0 + (tid >> 6)) * 64 + (tid & 63);
        const long xoff = (long)b * (C * 65536) + rg;   // x/out share layout

        // pw1 from global x (coalesced; L2/L3-hot under XCD swizzle).
        // Double-buffered groups of 8 -> 8 loads in flight, bounded regs.
        float s1[C8];
#pragma unroll
        for (int o = 0; o < C8; ++o) s1[o] = 0.f;
        float xg[2][8];
#pragma unroll
        for (int u = 0; u < 8; ++u) xg[0][u] = x[xoff + (long)u * 65536];
#pragma unroll
        for (int g = 0; g < 8; ++g) {
            const int cur = g & 1;
            if (g < 7) {
#pragma unroll
                for (int u = 0; u < 8; ++u)
                    xg[cur ^ 1][u] = x[xoff + (long)((g + 1) * 8 + u) * 65536];
            }
#pragma unroll
            for (int u = 0; u < 8; ++u) {
                const int ch = g * 8 + u;
                const float xc = xg[cur][u];
#pragma unroll
                for (int o = 0; o < C8; ++o) s1[o] += w1[o * C + ch] * xc;
            }
        }
        float hh[C8];
#pragma unroll
        for (int o = 0; o < C8; ++o) {
            const float sc = g2[o] * rsqrtf(va2[o] + EPSV);
            hh[o] = silu_f((s1[o] + b1[o] - mu2[o]) * sc + be2[o]);
        }

        // attn values (sort scratch only; epilogue recomputes identically)
        float t[C];
#pragma unroll
        for (int c = 0; c < C; ++c) {
            const float y1v = __half2float(y1s[c * 256 + (loc ^ ((c & 7) << 3))]);
            float y2 = b2[c];
#pragma unroll
            for (int o = 0; o < C8; ++o) y2 += w2[c * C8 + o] * hh[o];
            t[c] = y1v * y2;
        }

        // in-register bitonic sort (ascending) of 64 values — shuffle-free
#pragma unroll
        for (int k = 2; k <= 64; k <<= 1) {
#pragma unroll
            for (int j = k >> 1; j > 0; j >>= 1) {
#pragma unroll
                for (int i = 0; i < 64; ++i) {
                    const int l = i ^ j;
                    if (l > i) {
                        const float u = t[i], v = t[l];
                        const float mn = fminf(u, v), mx = fmaxf(u, v);
                        if ((i & k) == 0) { t[i] = mn; t[l] = mx; }
                        else              { t[i] = mx; t[l] = mn; }
                    }
                }
            }
        }
        const float thr = t[26];          // 38th largest of 64
        const float alpha = alphap[0];

        float* op = out + xoff;

        // epilogue: recompute attn (identical FMA order -> bitwise equal to
        // sorted values); x re-read from global (L1/L2-hot), groups of 8
#pragma unroll
        for (int u = 0; u < 8; ++u) xg[0][u] = x[xoff + (long)u * 65536];
#pragma unroll
        for (int g = 0; g < 8; ++g) {
            const int cur = g & 1;
            if (g < 7) {
#pragma unroll
                for (int u = 0; u < 8; ++u)
                    xg[cur ^ 1][u] = x[xoff + (long)((g + 1) * 8 + u) * 65536];
            }
#pragma unroll
            for (int u = 0; u < 8; ++u) {
                const int ch = g * 8 + u;
                const float y1v = __half2float(y1s[ch * 256 + (loc ^ ((ch & 7) << 3))]);
                float y2 = b2[ch];
#pragma unroll
                for (int o = 0; o < C8; ++o) y2 += w2[ch * C8 + o] * hh[o];
                const float av = y1v * y2;
                op[(long)ch * 65536] = xg[cur][u] + ((av >= thr) ? alpha * av : 0.f);
            }
        }
    }
}

extern "C" void kernel_launch(void* const* d_in, const int* in_sizes, int n_in,
                              void* d_out, int out_size, void* d_ws, size_t ws_size,
                              hipStream_t stream) {
    const float* x    = (const float*)d_in[0];
    const float* w_dw = (const float*)d_in[1];
    const float* g1   = (const float*)d_in[2];
    const float* be1  = (const float*)d_in[3];
    const float* mu1  = (const float*)d_in[4];
    const float* va1  = (const float*)d_in[5];
    const float* w1   = (const float*)d_in[6];
    const float* b1   = (const float*)d_in[7];
    const float* g2   = (const float*)d_in[8];
    const float* be2  = (const float*)d_in[9];
    const float* mu2  = (const float*)d_in[10];
    const float* va2  = (const float*)d_in[11];
    const float* w2   = (const float*)d_in[12];
    const float* b2   = (const float*)d_in[13];
    const float* alp  = (const float*)d_in[14];
    float* out = (float*)d_out;

    // grid: b(4) x d(16) x h-band(16) = 1024 blocks (XCD-swizzled in-kernel)
    fused_kernel<<<1024, 256, 0, stream>>>(
        x, w_dw, g1, be1, mu1, va1, w1, b1, g2, be2, mu2, va2, w2, b2, alp, out);
}